// Round 1
// 120.795 us; speedup vs baseline: 1.0420x; 1.0420x over previous
//
#include <hip/hip_runtime.h>
#include <math.h>

// EKF over 2048 trajectories, T=512 serial steps; lane 3k+j = subsystem j of
// trajectory k (21 traj/wave), three independent 2-state/1-meas Kalman
// filters per trajectory. Solo-wave blocks (no barriers), latency-bound.
//
// R9 (this round): the z tile no longer round-trips through LDS. Each lane's
// 32 z values are private (stride 12B in global), so they are prefetched one
// tile ahead straight into a register double-buffer (zA/zB) via 32
// global_load_dword with immediate offsets - removing per tile: 8 staging
// loads, 8 ds_write_b128, 32 bank-conflicted ds_read_b32, and their
// vmcnt/lgkmcnt drains. The recurrence is re-derived to shorten the binding
// loop-carried cycle (vel -> exp2 -> rcp -> tx -> t2 -> pp02 -> vel', 8 ops):
//   carry w = p00 + qp + r  =>  S = fma(DT, pu, w), pp00 = S - r,
//   w' = fma(-r*r, rs, 2r+qp)   (p00' = r - r^2*rs exactly),
//   pp02 = fma(cb*u, t2, fma(ca2,u,qc))  (t2 feeds pp02 in ONE fma).
// 28 VALU (3 trans) per step, zero memory ops in the step loop.

#define TRIPLES 21
#define TILE    32
#define SMS     35               // sSM row stride (float2)

__device__ __forceinline__ float frcp(float x) { return __builtin_amdgcn_rcpf(x); }

__global__ __launch_bounds__(64, 1) void ekf_kernel(
    const float* __restrict__ meas,        // (n_traj, T, 3)
    const float* __restrict__ init_state,  // (n_traj, 6)
    const float* __restrict__ dyna,        // (4,)
    const float* __restrict__ Qm,          // (6,6)
    const float* __restrict__ Rm,          // (3,3)
    const float* __restrict__ P0m,         // (6,6)
    float* __restrict__ out,               // (n_traj*T,)
    int n_traj, int T)
{
    // +2 pad rows: flush round rr=10/fhi=1 touches rows 63..65 (stores guarded,
    // reads must stay in-bounds now that zbuf no longer pads the allocation).
    __shared__ float2 sSM[66 * SMS];

    const int lane  = threadIdx.x;         // 0..63
    const int k     = lane / 3;
    const int j     = lane - 3 * k;        // subsystem 0=x,1=y,2=theta
    const int traj0 = blockIdx.x * TRIPLES;
    const int kk    = (k < TRIPLES) ? k : (TRIPLES - 1);
    const int traj  = traj0 + kk;
    const int traj_eff = (traj < n_traj) ? traj : (n_traj - 1);

    const int NT = T / TILE;               // 16
    const int T3 = 3 * T;

    // ---- filter constants (theta block is linear: ca=1, cf=0) ----
    const float DTc = 1.0f / 120.0f;
    const float Cc  = 288.53900817779268f; // 200/ln2: tanh(100v)=1-2/(exp2(Cc*v)+1)
    const float fric = dyna[0], damp = dyna[1];
    const bool  lin = (j == 2);
    const float ca  = lin ? 1.0f : (1.0f - DTc * damp);
    const float cf  = lin ? 0.0f : (DTc * fric);
    const float cb  = 100.0f * cf;
    const float ca2 = ca - cb;
    const int pi = (j == 0) ? 0 : (j == 1) ? 1 : 4;
    const int vi = pi + 2;
    const float qp = Qm[pi * 7], qv = Qm[vi * 7], qc = Qm[pi * 6 + vi];
    const float r   = Rm[j * 4];
    const float nr2 = -r * r;
    const float w0  = r + r + qp;          // w' = nr2*rs + w0
    float p02 = P0m[pi * 6 + vi], p22 = P0m[vi * 7];
    float w   = P0m[pi * 7] + qp + r;      // w = p00 + qp + r (carried)
    float pos = init_state[traj_eff * 6 + pi];
    float vel = init_state[traj_eff * 6 + vi];

    // ---- flush invariants: round rr covers rows ck = 2rr + (lane>>5) ----
    const int fhi  = lane >> 5;
    const int ftw  = lane & 31;
    const int fsm0 = 3 * fhi * SMS + ftw;              // float2 index, rr=0
    const int fob0 = (traj0 + fhi) * T + ftw;          // out float idx, rr=0

    // ---- per-lane z stream: stride-3 floats, prefetched a tile ahead ----
    const float* __restrict__ zlane = meas + (size_t)traj_eff * T3 + j;

    float zA[TILE], zB[TILE];
    #pragma unroll
    for (int tl = 0; tl < TILE; ++tl) zA[tl] = zlane[3 * tl];   // tile 0

#define EKF_PHASE(ZC, ZN, TIDX)                                              \
    do {                                                                     \
        const int tile_ = (TIDX);                                            \
        const int nt_   = (tile_ + 1 < NT) ? (tile_ + 1) : tile_;            \
        const float* __restrict__ znp_ = zlane + 96 * nt_;                   \
        _Pragma("unroll")                                                    \
        for (int tl = 0; tl < TILE; ++tl) ZN[tl] = znp_[3 * tl];             \
        float Sv[TILE], Mv[TILE];                                            \
        _Pragma("unroll")                                                    \
        for (int tl = 0; tl < TILE; ++tl) {                                  \
            const float z    = ZC[tl];                                       \
            const float e    = exp2f(Cc * vel);                              \
            const float ie   = frcp(e + 1.0f);                               \
            const float tx   = fmaf(-2.0f, ie, 1.0f);                        \
            const float t2   = tx * tx;                                      \
            const float u    = fmaf(DTc, p22, p02);                          \
            const float pu   = p02 + u;                                      \
            const float S    = fmaf(DTc, pu, w);    /* = pp00 + r */         \
            const float rs   = frcp(S);                                      \
            const float sp   = fmaf(DTc, vel, pos);                          \
            const float yv   = z - sp;                                       \
            const float rsy  = rs * yv;                                      \
            const float cbu  = cb * u;                                       \
            const float b02  = fmaf(ca2, u, qc);                             \
            const float pp02 = fmaf(cbu, t2, b02);                           \
            const float a    = fmaf(cb, t2, ca2);                            \
            const float ap   = a * p22;                                      \
            const float pp22 = fmaf(ap, a, qv);                              \
            const float sv   = fmaf(-cf, tx, ca * vel);                      \
            vel = fmaf(pp02, rsy, sv);                                       \
            const float pp00 = S - r;                                        \
            pos = fmaf(pp00, rsy, sp);                                       \
            w   = fmaf(nr2, rs, w0);                                         \
            const float gg   = r * rs;                                       \
            p02 = pp02 * gg;                                                 \
            const float k1   = pp02 * rs;                                    \
            p22 = fmaf(-k1, pp02, pp22);                                     \
            Sv[tl] = S;                                                      \
            Mv[tl] = yv * rsy;                                               \
        }                                                                    \
        /* burst-write (S,m) pairs to LDS (off the dependence chain) */      \
        float2* __restrict__ smr_ = &sSM[lane * SMS];                        \
        _Pragma("unroll")                                                    \
        for (int tl = 0; tl < TILE; ++tl)                                    \
            smr_[tl] = make_float2(Sv[tl], Mv[tl]);                          \
        /* flush: combine triples, coalesced stores (2 rows/round) */        \
        const int tb_ = tile_ * TILE;                                        \
        _Pragma("unroll")                                                    \
        for (int rr = 0; rr < 11; ++rr) {                                    \
            const int ck_ = 2 * rr + fhi;                                    \
            const bool ok_ = (rr * 64 + lane < TRIPLES * TILE) &&            \
                             (traj0 + ck_ < n_traj);                         \
            const int sa_ = fsm0 + rr * (6 * SMS);                           \
            const float2 a0_ = sSM[sa_];                                     \
            const float2 a1_ = sSM[sa_ + SMS];                               \
            const float2 a2_ = sSM[sa_ + 2 * SMS];                           \
            const float loss_ = (a0_.x * a1_.x) * a2_.x +                    \
                                (a0_.y + a1_.y + a2_.y);                     \
            if (ok_) out[(size_t)(fob0 + 2 * rr * T + tb_)] = loss_;         \
        }                                                                    \
    } while (0)

    #pragma unroll 1
    for (int th = 0; th < NT; th += 2) {
        EKF_PHASE(zA, zB, th);
        if (th + 1 < NT) EKF_PHASE(zB, zA, th + 1);
    }

#undef EKF_PHASE
}

extern "C" void kernel_launch(void* const* d_in, const int* in_sizes, int n_in,
                              void* d_out, int out_size, void* d_ws, size_t ws_size,
                              hipStream_t stream) {
    const float* meas = (const float*)d_in[0];
    const float* init_state = (const float*)d_in[1];
    const float* dyna = (const float*)d_in[2];
    const float* Qm  = (const float*)d_in[3];
    const float* Rm  = (const float*)d_in[4];
    const float* P0m = (const float*)d_in[5];
    float* out = (float*)d_out;

    const int n_traj = in_sizes[1] / 6;
    const int T = in_sizes[0] / (n_traj * 3);

    const int grid = (n_traj + TRIPLES - 1) / TRIPLES;
    ekf_kernel<<<grid, 64, 0, stream>>>(meas, init_state, dyna, Qm, Rm, P0m,
                                        out, n_traj, T);
}

// Round 2
// 117.836 us; speedup vs baseline: 1.0681x; 1.0251x over previous
//
#include <hip/hip_runtime.h>
#include <math.h>

// EKF over 2048 trajectories, T=512 serial steps; lane 3k+j = subsystem j of
// trajectory k (21 traj/wave), three independent 2-state/1-meas Kalman
// filters per trajectory. Solo-wave blocks (no barriers), latency-bound.
//
// R9: z prefetched one tile ahead straight into a register double-buffer
// (zA/zB); no LDS round-trip for z; w = p00 + qp + r carried so
// S = fma(DT,pu,w) and w' = fma(-r*r, rs, 2r+qp).
//
// R10 (this round): instruction-count discriminator. Step body cut 31 -> 27
// VALU (exact algebra, structure untouched):
//   - pp02 back to 2-op form: a = fma(cb,t2,ca2); pp02 = fma(a,u,qc)
//     (R9's cbu/b02 split spent +2 ops to shave 1 chain link)
//   - gg dropped: p02' = r*k1 with k1 = pp02*rs already needed for p22'
//   - Mv = yv*rsy (reuses rsy) instead of (yv*yv)*rs
// If issue/cadence-bound (low clock or solo-wave issue floor): expect ~-10%.
// If flat: dependency-latency-bound -> next round = packed-f32 2-chain/lane.

#define TRIPLES 21
#define TILE    32
#define SMS     35               // sSM row stride (float2)

__device__ __forceinline__ float frcp(float x) { return __builtin_amdgcn_rcpf(x); }

__global__ __launch_bounds__(64, 1) void ekf_kernel(
    const float* __restrict__ meas,        // (n_traj, T, 3)
    const float* __restrict__ init_state,  // (n_traj, 6)
    const float* __restrict__ dyna,        // (4,)
    const float* __restrict__ Qm,          // (6,6)
    const float* __restrict__ Rm,          // (3,3)
    const float* __restrict__ P0m,         // (6,6)
    float* __restrict__ out,               // (n_traj*T,)
    int n_traj, int T)
{
    // +2 pad rows: flush round rr=10/fhi=1 touches rows 63..65 (stores guarded,
    // reads must stay in-bounds).
    __shared__ float2 sSM[66 * SMS];

    const int lane  = threadIdx.x;         // 0..63
    const int k     = lane / 3;
    const int j     = lane - 3 * k;        // subsystem 0=x,1=y,2=theta
    const int traj0 = blockIdx.x * TRIPLES;
    const int kk    = (k < TRIPLES) ? k : (TRIPLES - 1);
    const int traj  = traj0 + kk;
    const int traj_eff = (traj < n_traj) ? traj : (n_traj - 1);

    const int NT = T / TILE;               // 16
    const int T3 = 3 * T;

    // ---- filter constants (theta block is linear: ca=1, cf=0) ----
    const float DTc = 1.0f / 120.0f;
    const float Cc  = 288.53900817779268f; // 200/ln2: tanh(100v)=1-2/(exp2(Cc*v)+1)
    const float fric = dyna[0], damp = dyna[1];
    const bool  lin = (j == 2);
    const float ca  = lin ? 1.0f : (1.0f - DTc * damp);
    const float cf  = lin ? 0.0f : (DTc * fric);
    const float cb  = 100.0f * cf;
    const float ca2 = ca - cb;
    const int pi = (j == 0) ? 0 : (j == 1) ? 1 : 4;
    const int vi = pi + 2;
    const float qp = Qm[pi * 7], qv = Qm[vi * 7], qc = Qm[pi * 6 + vi];
    const float r   = Rm[j * 4];
    const float nr2 = -r * r;
    const float w0  = r + r + qp;          // w' = nr2*rs + w0
    float p02 = P0m[pi * 6 + vi], p22 = P0m[vi * 7];
    float w   = P0m[pi * 7] + qp + r;      // w = p00 + qp + r (carried)
    float pos = init_state[traj_eff * 6 + pi];
    float vel = init_state[traj_eff * 6 + vi];

    // ---- flush invariants: round rr covers rows ck = 2rr + (lane>>5) ----
    const int fhi  = lane >> 5;
    const int ftw  = lane & 31;
    const int fsm0 = 3 * fhi * SMS + ftw;              // float2 index, rr=0
    const int fob0 = (traj0 + fhi) * T + ftw;          // out float idx, rr=0

    // ---- per-lane z stream: stride-3 floats, prefetched a tile ahead ----
    const float* __restrict__ zlane = meas + (size_t)traj_eff * T3 + j;

    float zA[TILE], zB[TILE];
    #pragma unroll
    for (int tl = 0; tl < TILE; ++tl) zA[tl] = zlane[3 * tl];   // tile 0

#define EKF_PHASE(ZC, ZN, TIDX)                                              \
    do {                                                                     \
        const int tile_ = (TIDX);                                            \
        const int nt_   = (tile_ + 1 < NT) ? (tile_ + 1) : tile_;            \
        const float* __restrict__ znp_ = zlane + 96 * nt_;                   \
        _Pragma("unroll")                                                    \
        for (int tl = 0; tl < TILE; ++tl) ZN[tl] = znp_[3 * tl];             \
        float Sv[TILE], Mv[TILE];                                            \
        _Pragma("unroll")                                                    \
        for (int tl = 0; tl < TILE; ++tl) {                                  \
            const float z    = ZC[tl];                                       \
            const float e    = exp2f(Cc * vel);                              \
            const float ie   = frcp(e + 1.0f);                               \
            const float tx   = fmaf(-2.0f, ie, 1.0f);                        \
            const float t2   = tx * tx;                                      \
            const float u    = fmaf(DTc, p22, p02);                          \
            const float pu   = p02 + u;                                      \
            const float S    = fmaf(DTc, pu, w);    /* = pp00 + r */         \
            const float rs   = frcp(S);                                      \
            const float sp   = fmaf(DTc, vel, pos);                          \
            const float yv   = z - sp;                                       \
            const float rsy  = rs * yv;                                      \
            const float a    = fmaf(cb, t2, ca2);                            \
            const float pp02 = fmaf(a, u, qc);                               \
            const float ap   = a * p22;                                      \
            const float pp22 = fmaf(ap, a, qv);                              \
            const float sv   = fmaf(-cf, tx, ca * vel);                      \
            vel = fmaf(pp02, rsy, sv);                                       \
            const float pp00 = S - r;                                        \
            pos = fmaf(pp00, rsy, sp);                                       \
            w   = fmaf(nr2, rs, w0);                                         \
            const float k1   = pp02 * rs;                                    \
            p02 = r * k1;                                                    \
            p22 = fmaf(-k1, pp02, pp22);                                     \
            Sv[tl] = S;                                                      \
            Mv[tl] = yv * rsy;                                               \
        }                                                                    \
        /* burst-write (S,m) pairs to LDS (off the dependence chain) */      \
        float2* __restrict__ smr_ = &sSM[lane * SMS];                        \
        _Pragma("unroll")                                                    \
        for (int tl = 0; tl < TILE; ++tl)                                    \
            smr_[tl] = make_float2(Sv[tl], Mv[tl]);                          \
        /* flush: combine triples, coalesced stores (2 rows/round) */        \
        const int tb_ = tile_ * TILE;                                        \
        _Pragma("unroll")                                                    \
        for (int rr = 0; rr < 11; ++rr) {                                    \
            const int ck_ = 2 * rr + fhi;                                    \
            const bool ok_ = (rr * 64 + lane < TRIPLES * TILE) &&            \
                             (traj0 + ck_ < n_traj);                         \
            const int sa_ = fsm0 + rr * (6 * SMS);                           \
            const float2 a0_ = sSM[sa_];                                     \
            const float2 a1_ = sSM[sa_ + SMS];                               \
            const float2 a2_ = sSM[sa_ + 2 * SMS];                           \
            const float loss_ = (a0_.x * a1_.x) * a2_.x +                    \
                                (a0_.y + a1_.y + a2_.y);                     \
            if (ok_) out[(size_t)(fob0 + 2 * rr * T + tb_)] = loss_;         \
        }                                                                    \
    } while (0)

    #pragma unroll 1
    for (int th = 0; th < NT; th += 2) {
        EKF_PHASE(zA, zB, th);
        if (th + 1 < NT) EKF_PHASE(zB, zA, th + 1);
    }

#undef EKF_PHASE
}

extern "C" void kernel_launch(void* const* d_in, const int* in_sizes, int n_in,
                              void* d_out, int out_size, void* d_ws, size_t ws_size,
                              hipStream_t stream) {
    const float* meas = (const float*)d_in[0];
    const float* init_state = (const float*)d_in[1];
    const float* dyna = (const float*)d_in[2];
    const float* Qm  = (const float*)d_in[3];
    const float* Rm  = (const float*)d_in[4];
    const float* P0m = (const float*)d_in[5];
    float* out = (float*)d_out;

    const int n_traj = in_sizes[1] / 6;
    const int T = in_sizes[0] / (n_traj * 3);

    const int grid = (n_traj + TRIPLES - 1) / TRIPLES;
    ekf_kernel<<<grid, 64, 0, stream>>>(meas, init_state, dyna, Qm, Rm, P0m,
                                        out, n_traj, T);
}

// Round 3
// 111.863 us; speedup vs baseline: 1.1252x; 1.0534x over previous
//
#include <hip/hip_runtime.h>
#include <math.h>

// EKF over 2048 trajectories, T=512 serial steps; lane 3k+j = subsystem j of
// trajectory k (21 traj/wave), three independent 2-state/1-meas Kalman
// filters per trajectory. Solo-wave blocks (no barriers); regime: ~80%
// issue-bound on a solo SIMD (R10 A/B: -4 VALU -> -6.6 cyc/step), rest
// dep-chain stall.
//
// R9:  z register double-buffer (no LDS round-trip), carried w = p00+qp+r.
// R10: 27-VALU step body (exact algebra cuts).
// R11 (this round):
//  - scaled space: carry xv = Cc*vel, posC = Cc*pos -> exp2 reads the carried
//    reg directly; yvC = fma(Cc, z, -spC); Mahalanobis descale (1/Cc^2) folds
//    into the flush fma. vel/pos never materialized.
//  - a = ca - 4cb*(ie - ie^2): t = fma(-ie,ie,ie); a = fma(-4cb,t,ca).
//    tanh/tx/t2 eliminated; carried cycle 44 -> 36 cyc; body 27 -> 25 VALU
//    (3 trans), zero memory ops.
//  - (S,m) packed 2 steps/float4: 16 ds_write_b128 + 18 ds_read_b128 +
//    6 float2 stores per tile (was 32 b64 writes + 33 b64 reads + 11 stores).
//  - theta velocity index fixed 6 -> 5 (was OOB into Qm/P0m/init_state;
//    outputs move toward the JAX reference).

#define TRIPLES 21
#define TILE    32
#define SMS4    17               // sSM4 row stride in float4 (16 pairs + 1 pad)

__device__ __forceinline__ float frcp(float x) { return __builtin_amdgcn_rcpf(x); }

__global__ __launch_bounds__(64, 1) void ekf_kernel(
    const float* __restrict__ meas,        // (n_traj, T, 3)
    const float* __restrict__ init_state,  // (n_traj, 6)
    const float* __restrict__ dyna,        // (4,)
    const float* __restrict__ Qm,          // (6,6)
    const float* __restrict__ Rm,          // (3,3)
    const float* __restrict__ P0m,         // (6,6)
    float* __restrict__ out,               // (n_traj*T,)
    int n_traj, int T)
{
    // 72 rows: flush round rr=5 reads rows up to 3*23+2 = 71 (stores guarded,
    // reads must stay in-bounds; rows >= 63 hold garbage, never stored).
    __shared__ float4 sSM4[72 * SMS4];     // 19,584 B

    const int lane  = threadIdx.x;         // 0..63
    const int k     = lane / 3;
    const int j     = lane - 3 * k;        // subsystem 0=x,1=y,2=theta
    const int traj0 = blockIdx.x * TRIPLES;
    const int kk    = (k < TRIPLES) ? k : (TRIPLES - 1);
    const int traj  = traj0 + kk;
    const int traj_eff = (traj < n_traj) ? traj : (n_traj - 1);

    const int NT = T / TILE;               // 16
    const int T3 = 3 * T;

    // ---- filter constants (theta block is linear: ca=1, cf=0) ----
    const float DTc = 1.0f / 120.0f;
    const float Cc  = 288.53900817779268f; // 200/ln2
    const float invCc2 = 1.0f / (Cc * Cc); // compile-time folded
    const float fric = dyna[0], damp = dyna[1];
    const bool  lin = (j == 2);
    const float ca  = lin ? 1.0f : (1.0f - DTc * damp);
    const float cf  = lin ? 0.0f : (DTc * fric);
    const float cb  = 100.0f * cf;
    const float m4cb  = -4.0f * cb;
    const float cf2Cc = 2.0f * (cf * Cc);
    const float mcfCc = -(cf * Cc);
    const int pi = (j == 0) ? 0 : (j == 1) ? 1 : 4;
    const int vi = lin ? 5 : (pi + 2);     // R11: theta velocity is state 5
    const float qp = Qm[pi * 7], qv = Qm[vi * 7], qc = Qm[pi * 6 + vi];
    const float r   = Rm[j * 4];
    const float nr2 = -r * r;
    const float w0  = r + r + qp;          // w' = nr2*rs + w0
    float p02 = P0m[pi * 6 + vi], p22 = P0m[vi * 7];
    float w   = P0m[pi * 7] + qp + r;      // w = p00 + qp + r (carried)
    float posC = Cc * init_state[traj_eff * 6 + pi];
    float xv   = Cc * init_state[traj_eff * 6 + vi];

    // ---- flush mapping: 4 traj rows/round, 16 t-pairs/row, float2 stores ----
    const int fh = lane >> 4;              // 0..3 traj row within round
    const int tw = lane & 15;              // t-pair index
    const int fb0 = (3 * fh) * SMS4 + tw;  // float4 index, rr=0, subsys 0
    float* const obase = out + (size_t)(traj0 + fh) * T + 2 * tw;

    // ---- per-lane z stream: stride-3 floats, prefetched a tile ahead ----
    const float* __restrict__ zlane = meas + (size_t)traj_eff * T3 + j;

    float zA[TILE], zB[TILE];
    #pragma unroll
    for (int tl = 0; tl < TILE; ++tl) zA[tl] = zlane[3 * tl];   // tile 0

#define EKF_PHASE(ZC, ZN, TIDX)                                              \
    do {                                                                     \
        const int tile_ = (TIDX);                                            \
        const int nt_   = (tile_ + 1 < NT) ? (tile_ + 1) : tile_;            \
        const float* __restrict__ znp_ = zlane + 96 * nt_;                   \
        _Pragma("unroll")                                                    \
        for (int tl = 0; tl < TILE; ++tl) ZN[tl] = znp_[3 * tl];             \
        float Sv[TILE], Mv[TILE];                                            \
        _Pragma("unroll")                                                    \
        for (int tl = 0; tl < TILE; ++tl) {                                  \
            const float z    = ZC[tl];                                       \
            const float e    = exp2f(xv);           /* 2^(Cc*vel) */         \
            const float ie   = frcp(e + 1.0f);                               \
            const float t    = fmaf(-ie, ie, ie);   /* ie - ie^2 */          \
            const float a    = fmaf(m4cb, t, ca);                            \
            const float u    = fmaf(DTc, p22, p02);                          \
            const float wp   = fmaf(DTc, p02, w);                            \
            const float S    = fmaf(DTc, u, wp);    /* = pp00 + r */         \
            const float rs   = frcp(S);                                      \
            const float spC  = fmaf(DTc, xv, posC);                          \
            const float yvC  = fmaf(Cc, z, -spC);                            \
            const float rsyC = rs * yvC;                                     \
            const float pp02 = fmaf(a, u, qc);                               \
            const float ap   = a * p22;                                      \
            const float pp22 = fmaf(ap, a, qv);                              \
            const float sviC = fmaf(ca, xv, mcfCc);                          \
            const float svC  = fmaf(cf2Cc, ie, sviC);                        \
            xv   = fmaf(pp02, rsyC, svC);                                    \
            const float pp00 = S - r;                                        \
            posC = fmaf(pp00, rsyC, spC);                                    \
            w    = fmaf(nr2, rs, w0);                                        \
            const float k1 = pp02 * rs;                                      \
            p02 = r * k1;                                                    \
            p22 = fmaf(-k1, pp02, pp22);                                     \
            Sv[tl] = S;                                                      \
            Mv[tl] = yvC * rsyC;   /* Cc^2 * y^2/S, descaled at flush */     \
        }                                                                    \
        /* burst-write packed (S,m) pairs: 16 ds_write_b128 */               \
        _Pragma("unroll")                                                    \
        for (int h = 0; h < TILE / 2; ++h)                                   \
            sSM4[lane * SMS4 + h] =                                          \
                make_float4(Sv[2*h], Mv[2*h], Sv[2*h+1], Mv[2*h+1]);         \
        /* flush: 6 rounds x (3 ds_read_b128 + float2 store) */              \
        const int tb_ = tile_ * TILE;                                        \
        _Pragma("unroll")                                                    \
        for (int rr = 0; rr < 6; ++rr) {                                     \
            const int ck_ = 4 * rr + fh;                                     \
            const bool ok_ = (ck_ < TRIPLES) && (traj0 + ck_ < n_traj);      \
            const float4 a0_ = sSM4[fb0 + 204 * rr];                         \
            const float4 a1_ = sSM4[fb0 + 204 * rr + SMS4];                  \
            const float4 a2_ = sSM4[fb0 + 204 * rr + 2 * SMS4];              \
            const float l0_ = fmaf(a0_.y + a1_.y + a2_.y, invCc2,            \
                                   (a0_.x * a1_.x) * a2_.x);                 \
            const float l1_ = fmaf(a0_.w + a1_.w + a2_.w, invCc2,            \
                                   (a0_.z * a1_.z) * a2_.z);                 \
            if (ok_) *(float2*)(obase + tb_ + rr * (4 * T)) =                \
                make_float2(l0_, l1_);                                       \
        }                                                                    \
    } while (0)

    #pragma unroll 1
    for (int th = 0; th < NT; th += 2) {
        EKF_PHASE(zA, zB, th);
        if (th + 1 < NT) EKF_PHASE(zB, zA, th + 1);
    }

#undef EKF_PHASE
}

extern "C" void kernel_launch(void* const* d_in, const int* in_sizes, int n_in,
                              void* d_out, int out_size, void* d_ws, size_t ws_size,
                              hipStream_t stream) {
    const float* meas = (const float*)d_in[0];
    const float* init_state = (const float*)d_in[1];
    const float* dyna = (const float*)d_in[2];
    const float* Qm  = (const float*)d_in[3];
    const float* Rm  = (const float*)d_in[4];
    const float* P0m = (const float*)d_in[5];
    float* out = (float*)d_out;

    const int n_traj = in_sizes[1] / 6;
    const int T = in_sizes[0] / (n_traj * 3);

    const int grid = (n_traj + TRIPLES - 1) / TRIPLES;
    ekf_kernel<<<grid, 64, 0, stream>>>(meas, init_state, dyna, Qm, Rm, P0m,
                                        out, n_traj, T);
}